// Round 16
// baseline (843.816 us; speedup 1.0000x reference)
//
#include <hip/hip_runtime.h>
#include <hip/hip_bf16.h>
#include <type_traits>

typedef __hip_bfloat16 bf16;
typedef __attribute__((ext_vector_type(8))) short s16x8;   // 8 bf16 (4 VGPRs)
typedef __attribute__((ext_vector_type(4))) float f32x4;

#define N_DET 16384
#define DIN   256
#define DD    1024
#define KSLOT 64
#define HH    2048
#define TD    3072
#define CHAIN_BLOCKS 96

__device__ __forceinline__ float b2f(bf16 x){ return __bfloat162float(x); }
__device__ __forceinline__ bf16  f2b(float x){ return __float2bfloat16(x); }
__device__ __forceinline__ float bits2f(short u){ return __uint_as_float(((unsigned)(unsigned short)u) << 16); }

__device__ __forceinline__ void gload_lds16(const void* g, void* l) {
  __builtin_amdgcn_global_load_lds(
      (const __attribute__((address_space(1))) unsigned int*)g,
      (__attribute__((address_space(3))) unsigned int*)l, 16, 0, 0);
}

// ---- manual grid barrier: monotonic counter, device-scope atomics (96 blocks co-resident) ----
__device__ __forceinline__ void gsync(int* bar, int n) {
  __syncthreads();
  if (threadIdx.x == 0) {
    __threadfence();
    atomicAdd(bar, 1);
    while (atomicAdd(bar, 0) < n * CHAIN_BLOCKS) { __builtin_amdgcn_s_sleep(1); }
    __threadfence();
  }
  __syncthreads();
}

// ================= big-GEMM compute: 128x128 tile, BK=64, XOR-swizzled LDS (proven) =================
__device__ __forceinline__ void big_compute(bf16* As, bf16* Bs,
    const bf16* __restrict__ Ap, const bf16* __restrict__ Bp, int K, f32x4 acc[4][4])
{
  const int tid = threadIdx.x;
  const int lane = tid & 63, wave = tid >> 6;
  const int wr = wave >> 1, wc = wave & 1;
  const int l15 = lane & 15, h = lane >> 4;
  const int rr = tid >> 3;
  const int qs = ((tid & 7) ^ (rr & 7)) * 8;

#pragma unroll
  for (int m = 0; m < 4; ++m)
#pragma unroll
    for (int n = 0; n < 4; ++n) acc[m][n] = {0.f, 0.f, 0.f, 0.f};

  for (int k0 = 0; k0 < K; k0 += 64) {
    __syncthreads();
#pragma unroll
    for (int g = 0; g < 4; ++g)
      gload_lds16(Ap + (size_t)(g * 32 + rr) * K + k0 + qs,
                  As + ((size_t)g * 256 + wave * 64) * 8);
#pragma unroll
    for (int g = 0; g < 4; ++g)
      gload_lds16(Bp + (size_t)(g * 32 + rr) * K + k0 + qs,
                  Bs + ((size_t)g * 256 + wave * 64) * 8);
    __syncthreads();

#pragma unroll
    for (int ks = 0; ks < 2; ++ks) {
      s16x8 af[4], bfr[4];
#pragma unroll
      for (int m = 0; m < 4; ++m) {
        int row = wr * 64 + m * 16 + l15;
        af[m] = *(const s16x8*)&As[row * 64 + (((ks * 4 + h) ^ (l15 & 7)) * 8)];
      }
#pragma unroll
      for (int n = 0; n < 4; ++n) {
        int row = wc * 64 + n * 16 + l15;
        bfr[n] = *(const s16x8*)&Bs[row * 64 + (((ks * 4 + h) ^ (l15 & 7)) * 8)];
      }
#pragma unroll
      for (int m = 0; m < 4; ++m)
#pragma unroll
        for (int n = 0; n < 4; ++n)
          acc[m][n] = __builtin_amdgcn_mfma_f32_16x16x32_bf16(af[m], bfr[n], acc[m][n], 0, 0, 0);
    }
  }
}

__device__ __forceinline__ void big_epilogue(int bm, int bn,
    const float* __restrict__ bias, bf16* __restrict__ C, int N, f32x4 acc[4][4])
{
  const int lane = threadIdx.x & 63, wave = threadIdx.x >> 6;
  const int wr = wave >> 1, wc = wave & 1;
#pragma unroll
  for (int m = 0; m < 4; ++m)
#pragma unroll
    for (int n = 0; n < 4; ++n) {
      int col = bn + wc * 64 + n * 16 + (lane & 15);
      float bv = bias ? bias[col] : 0.f;
#pragma unroll
      for (int j = 0; j < 4; ++j) {
        int row = bm + wr * 64 + m * 16 + (lane >> 4) * 4 + j;
        C[(size_t)row * N + col] = f2b(acc[m][n][j] + bv);
      }
    }
}

__device__ __forceinline__ void big_gemm_body(int wg, int nct,
    const bf16* __restrict__ A, const bf16* __restrict__ Bt,
    const float* __restrict__ bias, bf16* __restrict__ C, int N, int K,
    bf16* As, bf16* Bs)
{
  const int bn = (wg % nct) * 128;
  const int bm = (wg / nct) * 128;
  f32x4 acc[4][4];
  big_compute(As, Bs, A + (size_t)bm * K, Bt + (size_t)bn * K, K, acc);
  big_epilogue(bm, bn, bias, C, N, acc);
}

// ---------------- enc GEMM: A f32 converted in-reg (proven R14 form, BK=64) ----------------
__global__ __launch_bounds__(256) void gemm_enc(
    const float* __restrict__ A, const bf16* __restrict__ Bt,
    const float* __restrict__ bias, bf16* __restrict__ C, int M, int N, int K)
{
  const int nct = N >> 7;
  const int chunk = gridDim.x >> 3;
  const int wg = (blockIdx.x & 7) * chunk + (blockIdx.x >> 3);
  const int bn = (wg % nct) * 128;
  const int bm = (wg / nct) * 128;

  __shared__ bf16 As[128 * 64];
  __shared__ bf16 Bs[128 * 64];
  const int tid = threadIdx.x;
  const int lane = tid & 63, wave = tid >> 6;
  const int l15 = lane & 15, h = lane >> 4;
  const int wr = wave >> 1, wc = wave & 1;
  const int rr = tid >> 3;
  const int qs = ((tid & 7) ^ (rr & 7)) * 8;

  f32x4 acc[4][4];
#pragma unroll
  for (int m = 0; m < 4; ++m)
#pragma unroll
    for (int n = 0; n < 4; ++n) acc[m][n] = {0.f, 0.f, 0.f, 0.f};

  for (int k0 = 0; k0 < K; k0 += 64) {
    __syncthreads();
#pragma unroll
    for (int g = 0; g < 4; ++g) {
      const float* src = A + (size_t)(bm + g * 32 + rr) * K + k0 + qs;
      float4 f0 = *(const float4*)src;
      float4 f1 = *(const float4*)(src + 4);
      bf16 pk[8] = {f2b(f0.x), f2b(f0.y), f2b(f0.z), f2b(f0.w),
                    f2b(f1.x), f2b(f1.y), f2b(f1.z), f2b(f1.w)};
      *(s16x8*)&As[g * 2048 + tid * 8] = *(const s16x8*)pk;
    }
#pragma unroll
    for (int g = 0; g < 4; ++g)
      gload_lds16(Bt + (size_t)(bn + g * 32 + rr) * K + k0 + qs,
                  Bs + ((size_t)g * 256 + wave * 64) * 8);
    __syncthreads();

#pragma unroll
    for (int ks = 0; ks < 2; ++ks) {
      s16x8 af[4], bfr[4];
#pragma unroll
      for (int m = 0; m < 4; ++m) {
        int row = wr * 64 + m * 16 + l15;
        af[m] = *(const s16x8*)&As[row * 64 + (((ks * 4 + h) ^ (l15 & 7)) * 8)];
      }
#pragma unroll
      for (int n = 0; n < 4; ++n) {
        int row = wc * 64 + n * 16 + l15;
        bfr[n] = *(const s16x8*)&Bs[row * 64 + (((ks * 4 + h) ^ (l15 & 7)) * 8)];
      }
#pragma unroll
      for (int m = 0; m < 4; ++m)
#pragma unroll
        for (int n = 0; n < 4; ++n)
          acc[m][n] = __builtin_amdgcn_mfma_f32_16x16x32_bf16(af[m], bfr[n], acc[m][n], 0, 0, 0);
    }
  }
  big_epilogue(bm, bn, bias, C, N, acc);
}

// ---------------- merged setup GEMMs ----------------
__global__ __launch_bounds__(256) void gemm_setup_pair(
    const bf16* __restrict__ Wi_b, const bf16* __restrict__ Wv_bf, bf16* __restrict__ Wvit,
    const bf16* __restrict__ Wk_bf, const bf16* __restrict__ Wq_bf, bf16* __restrict__ Wqk_t)
{
  __shared__ bf16 As[128 * 64];
  __shared__ bf16 Bs[128 * 64];
  if (blockIdx.x < 192) {
    int bid = blockIdx.x;
    int wg = (bid & 7) * 24 + (bid >> 3);
    big_gemm_body(wg, 8, Wi_b, Wv_bf, nullptr, Wvit, DD, DD, As, Bs);
  } else {
    int bid = blockIdx.x - 192;
    int wg = (bid & 7) * 8 + (bid >> 3);
    big_gemm_body(wg, 8, Wk_bf, Wq_bf, nullptr, Wqk_t, DD, DD, As, Bs);
  }
}

// ================= skinny split-K MFMA: proven layout, BK=256/barrier =================
__device__ __forceinline__ void skinny_compute(bf16* As, bf16* Bs,
    const bf16* __restrict__ A, const bf16* __restrict__ Bt,
    int K, int Kc, int n0, int kb0, f32x4 acc[4])
{
  const int tid = threadIdx.x;
  const int lane = tid & 63, wave = tid >> 6;
  const int rem = wave * 64 + lane;
  const int r = rem >> 2, q = rem & 3;
  const int l15 = lane & 15, h = lane >> 4;

#pragma unroll
  for (int m = 0; m < 4; ++m) acc[m] = {0.f, 0.f, 0.f, 0.f};

  for (int kb = kb0; kb < kb0 + Kc; kb += 256) {
    __syncthreads();
#pragma unroll
    for (int half = 0; half < 2; ++half) {
#pragma unroll
      for (int g = 0; g < 4; ++g)
        gload_lds16(A + (size_t)r * K + kb + half * 128 + g * 32 + q * 8,
                    As + (size_t)half * 8192 + ((size_t)g * 256 + wave * 64) * 8);
#pragma unroll
      for (int g = 0; g < 4; ++g)
        gload_lds16(Bt + (size_t)(n0 + r) * K + kb + half * 128 + g * 32 + q * 8,
                    Bs + (size_t)half * 8192 + ((size_t)g * 256 + wave * 64) * 8);
    }
    __syncthreads();

#pragma unroll
    for (int half = 0; half < 2; ++half)
#pragma unroll
      for (int ks = 0; ks < 4; ++ks) {
        s16x8 bfr = *(const s16x8*)&Bs[half * 8192 + (ks * 64 + wave * 16 + l15) * 32 + h * 8];
#pragma unroll
        for (int m = 0; m < 4; ++m) {
          s16x8 af = *(const s16x8*)&As[half * 8192 + (ks * 64 + m * 16 + l15) * 32 + h * 8];
          acc[m] = __builtin_amdgcn_mfma_f32_16x16x32_bf16(af, bfr, acc[m], 0, 0, 0);
        }
      }
  }
}

// EPI: 0 = f32 partial @ row blockIdx.y*64; 1 = bf16 + bias (standalone qk0 / updates) ----------------
template<int EPI>
__global__ __launch_bounds__(256) void gemm_skinny_e(
    const bf16* __restrict__ A, const bf16* __restrict__ Bt,
    float* __restrict__ pbuf, bf16* __restrict__ outb,
    const float* __restrict__ bias, int N, int K, int Kc)
{
  __shared__ bf16 As[2 * 4 * 64 * 32];
  __shared__ bf16 Bs[2 * 4 * 64 * 32];
  f32x4 acc[4];
  skinny_compute(As, Bs, A, Bt, K, Kc, blockIdx.x * 64, blockIdx.y * Kc, acc);

  const int lane = threadIdx.x & 63, wave = threadIdx.x >> 6;
  const int l15 = lane & 15, h = lane >> 4;
#pragma unroll
  for (int m = 0; m < 4; ++m)
#pragma unroll
    for (int j = 0; j < 4; ++j) {
      int row = m * 16 + h * 4 + j;
      int col = blockIdx.x * 64 + wave * 16 + l15;
      if (EPI == 0) {
        pbuf[((size_t)(blockIdx.y * 64) + row) * N + col] = acc[m][j];
      } else {
        float v = acc[m][j] + bias[col];
        outb[(size_t)row * N + col] = f2b(v);
      }
    }
}

// ---------------- block LN helper; optional: cbuf[row]=ln_row·wqbk, colsum[row]=0 ----------------
__device__ __forceinline__ void block_ln_store(float v[4], float s, float sq,
    bf16* __restrict__ out, int row,
    const float* __restrict__ wqbk, float* __restrict__ cbuf, float* __restrict__ colsum)
{
  for (int o = 32; o > 0; o >>= 1) { s += __shfl_down(s, o, 64); sq += __shfl_down(sq, o, 64); }
  __shared__ float ls[4], lq[4];
  int w = threadIdx.x >> 6;
  if ((threadIdx.x & 63) == 0) { ls[w] = s; lq[w] = sq; }
  __syncthreads();
  s  = ls[0] + ls[1] + ls[2] + ls[3];
  sq = lq[0] + lq[1] + lq[2] + lq[3];
  float mu = s * (1.f / DD);
  float var = sq * (1.f / DD) - mu * mu;
  float rstd = rsqrtf(var + 1e-5f);
#pragma unroll
  for (int j = 0; j < 4; j++)
    out[(size_t)row * DD + threadIdx.x + j * 256] = f2b((v[j] - mu) * rstd);
  if (wqbk) {
    float dot = 0.f;
#pragma unroll
    for (int j = 0; j < 4; j++) dot += (v[j] - mu) * rstd * wqbk[threadIdx.x + j * 256];
    for (int o = 32; o > 0; o >>= 1) dot += __shfl_down(dot, o, 64);
    __syncthreads();
    if ((threadIdx.x & 63) == 0) ls[w] = dot;
    __syncthreads();
    if (threadIdx.x == 0) { cbuf[row] = ls[0] + ls[1] + ls[2] + ls[3]; colsum[row] = 0.f; }
  }
}

// ---------------- slots init (frame 1 only) ----------------
__global__ __launch_bounds__(256) void slots_init_ln(const float* __restrict__ mu,
    const float* __restrict__ noise, float* __restrict__ slots,
    bf16* __restrict__ slotspb, bf16* __restrict__ lnb,
    const float* __restrict__ wqbk, float* __restrict__ cbuf, float* __restrict__ colsum)
{
  int s = blockIdx.x, t = threadIdx.x;
  float v[4], sum = 0.f, sq = 0.f;
#pragma unroll
  for (int j = 0; j < 4; ++j) {
    int d = t + j * 256;
    float x = mu[d] + noise[(size_t)s * DD + d];
    slots[(size_t)s * DD + d] = x;
    slotspb[(size_t)s * DD + d] = f2b(x);
    v[j] = x; sum += x; sq += x * x;
  }
  block_ln_store(v, sum, sq, lnb, s, wqbk, cbuf, colsum);
}

// ---------------- iter_chain: updates_reduce -> dual GEMM -> GRU+LN -> W1 -> W2 -> MLP2+LN -> qk GEMM ----------------
__global__ __launch_bounds__(256) void iter_chain(
    const float* __restrict__ pU, float* __restrict__ colsum, float* __restrict__ cbuf,
    bf16* __restrict__ tb,
    const bf16* __restrict__ Wvit, const bf16* __restrict__ Wh_b,
    float* __restrict__ p0, float* __restrict__ p1,
    const float* __restrict__ bvi, const float* __restrict__ bh,
    float* __restrict__ slots, bf16* __restrict__ lnb,
    const bf16* __restrict__ W1_t, const float* __restrict__ b1, bf16* __restrict__ hidb,
    const bf16* __restrict__ W2_t, float* __restrict__ pW2,
    const float* __restrict__ b2, bf16* __restrict__ slotspb,
    const float* __restrict__ wqbk,
    const bf16* __restrict__ Wqk_t, const float* __restrict__ bqk, bf16* __restrict__ qkb,
    float* __restrict__ prevs, int save_prevs,
    int* __restrict__ bar, int barBase)
{
  __shared__ bf16 As[2 * 4 * 64 * 32];
  __shared__ bf16 Bs[2 * 4 * 64 * 32];
  const int bid = blockIdx.x, tid = threadIdx.x;
  const int lane = tid & 63, wave = tid >> 6;
  const int l15 = lane & 15, h = lane >> 4;
  int bno = barBase;

  // S_A: tb = reduce16(pU) / (colsum+eps)
  for (int idx = bid * 256 + tid; idx < KSLOT * DD; idx += CHAIN_BLOCKS * 256) {
    int s = idx >> 10, d = idx & 1023;
    float v = 0.f;
#pragma unroll
    for (int sk = 0; sk < 16; ++sk) v += pU[(size_t)(sk * 64 + s) * DD + d];
    tb[(size_t)s * DD + d] = f2b(v / (colsum[s] + 1e-8f));
  }
  gsync(bar, ++bno);

  // S_B: dual GEMM (z=0: tb@Wvit -> p0; z=1: slotspb@Wh -> p1)
  {
    int z = bid >= 48, bx = z ? bid - 48 : bid;
    f32x4 acc[4];
    skinny_compute(As, Bs, z ? slotspb : tb, z ? Wh_b : Wvit, DD, DD, bx * 64, 0, acc);
    float* p = z ? p1 : p0;
#pragma unroll
    for (int m = 0; m < 4; ++m)
#pragma unroll
      for (int j = 0; j < 4; ++j) {
        int row = m * 16 + h * 4 + j;
        int col = bx * 64 + wave * 16 + l15;
        p[(size_t)row * TD + col] = acc[m][j];
      }
  }
  gsync(bar, ++bno);

  // S_C: GRU + LN (64 blocks)
  if (bid < 64) {
    int s = bid;
    float v[4], sum = 0.f, sq = 0.f;
#pragma unroll
    for (int j = 0; j < 4; ++j) {
      int d = tid + j * 256;
      const float* a = p0 + (size_t)s * TD;
      const float* b = p1 + (size_t)s * TD;
      float ir = bvi[d] + a[d], iz = bvi[1024 + d] + a[1024 + d], in_ = bvi[2048 + d] + a[2048 + d];
      float hr = bh[d] + b[d], hz = bh[1024 + d] + b[1024 + d], hnn = bh[2048 + d] + b[2048 + d];
      float r = 1.f / (1.f + expf(-(ir + hr)));
      float z = 1.f / (1.f + expf(-(iz + hz)));
      float nn = tanhf(in_ + r * hnn);
      float hld = slots[(size_t)s * DD + d];
      float hv = (1.f - z) * nn + z * hld;
      slots[(size_t)s * DD + d] = hv;
      v[j] = hv; sum += hv; sq += hv * hv;
    }
    block_ln_store(v, sum, sq, lnb, s, nullptr, nullptr, nullptr);
  }
  gsync(bar, ++bno);

  // S_D: W1 GEMM + relu -> hidb (32 blocks)
  if (bid < 32) {
    f32x4 acc[4];
    skinny_compute(As, Bs, lnb, W1_t, DD, DD, bid * 64, 0, acc);
#pragma unroll
    for (int m = 0; m < 4; ++m)
#pragma unroll
      for (int j = 0; j < 4; ++j) {
        int row = m * 16 + h * 4 + j;
        int col = bid * 64 + wave * 16 + l15;
        hidb[(size_t)row * HH + col] = f2b(fmaxf(acc[m][j] + b1[col], 0.f));
      }
  }
  gsync(bar, ++bno);

  // S_E: W2 GEMM partials (32 blocks: 16 n-tiles x 2 K-chunks)
  if (bid < 32) {
    int bx = bid & 15, by = bid >> 4;
    f32x4 acc[4];
    skinny_compute(As, Bs, hidb, W2_t, HH, 1024, bx * 64, by * 1024, acc);
#pragma unroll
    for (int m = 0; m < 4; ++m)
#pragma unroll
      for (int j = 0; j < 4; ++j) {
        int row = m * 16 + h * 4 + j;
        int col = bx * 64 + wave * 16 + l15;
        pW2[((size_t)(by * 64) + row) * DD + col] = acc[m][j];
      }
  }
  gsync(bar, ++bno);

  // S_F: MLP2 reduce + resid + LN + slotspb + cbuf/colsum (+prevs) (64 blocks)
  if (bid < 64) {
    int s = bid;
    float v[4], sum = 0.f, sq = 0.f;
#pragma unroll
    for (int j = 0; j < 4; ++j) {
      int d = tid + j * 256;
      float x = b2[d] + slots[(size_t)s * DD + d];
#pragma unroll
      for (int sk = 0; sk < 2; ++sk) x += pW2[(size_t)(sk * 64 + s) * DD + d];
      slots[(size_t)s * DD + d] = x;
      slotspb[(size_t)s * DD + d] = f2b(x);
      if (save_prevs) prevs[(size_t)s * DD + d] = x;
      v[j] = x; sum += x; sq += x * x;
    }
    block_ln_store(v, sum, sq, lnb, s, wqbk, cbuf, colsum);
  }
  gsync(bar, ++bno);

  // S_G: qk GEMM for next iteration: qkb = lnb @ Wqk^T + bqk (16 blocks)
  if (bid < 16) {
    f32x4 acc[4];
    skinny_compute(As, Bs, lnb, Wqk_t, DD, DD, bid * 64, 0, acc);
#pragma unroll
    for (int m = 0; m < 4; ++m)
#pragma unroll
      for (int j = 0; j < 4; ++j) {
        int row = m * 16 + h * 4 + j;
        int col = bid * 64 + wave * 16 + l15;
        qkb[(size_t)row * DD + col] = f2b(acc[m][j] + bqk[col]);
      }
  }
}

// ---------------- fused QK^T(+c) + softmax(axis=slots) + colsum — proven layout, BK=256/barrier ----------------
__global__ __launch_bounds__(256) void qk_softmax(const bf16* __restrict__ qkb,
    const bf16* __restrict__ x, const float* __restrict__ cbuf,
    bf16* __restrict__ attn, float* __restrict__ colsum)
{
  __shared__ bf16 Qs[4 * 64 * 64];
  __shared__ bf16 Ks[4 * 64 * 64];
  __shared__ float cs[64], cl[64];
  const int t = threadIdx.x, lane = t & 63, wave = t >> 6;
  const int n0 = blockIdx.x * 64;
  const int l15 = lane & 15, h = lane >> 4;
  if (t < 64) { cs[t] = 0.f; cl[t] = cbuf[t]; }

  f32x4 acc[4];
#pragma unroll
  for (int m = 0; m < 4; ++m) acc[m] = {0.f, 0.f, 0.f, 0.f};

  for (int k0 = 0; k0 < DD; k0 += 256) {
    __syncthreads();
#pragma unroll
    for (int half = 0; half < 4; ++half) {
#pragma unroll
      for (int c = 0; c < 2; ++c) {
        int i = c * 256 + t;
        int r = i >> 3, q8 = i & 7;
        gload_lds16(qkb + (size_t)r * DD + k0 + half * 64 + q8 * 8,
                    Qs + (size_t)half * 4096 + ((size_t)c * 256 + wave * 64) * 8);
      }
#pragma unroll
      for (int c = 0; c < 2; ++c) {
        int i = c * 256 + t;
        int r = i >> 3, q8 = i & 7;
        gload_lds16(x + (size_t)(n0 + r) * DD + k0 + half * 64 + q8 * 8,
                    Ks + (size_t)half * 4096 + ((size_t)c * 256 + wave * 64) * 8);
      }
    }
    __syncthreads();

#pragma unroll
    for (int half = 0; half < 4; ++half)
#pragma unroll
      for (int ks = 0; ks < 2; ++ks) {
        s16x8 bfr = *(const s16x8*)&Ks[half * 4096 + (wave * 16 + l15) * 64 + ks * 32 + h * 8];
#pragma unroll
        for (int m = 0; m < 4; ++m) {
          s16x8 af = *(const s16x8*)&Qs[half * 4096 + (m * 16 + l15) * 64 + ks * 32 + h * 8];
          acc[m] = __builtin_amdgcn_mfma_f32_16x16x32_bf16(af, bfr, acc[m], 0, 0, 0);
        }
      }
  }

  float e[4][4];
  float cmax = -1e30f;
#pragma unroll
  for (int m = 0; m < 4; ++m)
#pragma unroll
    for (int j = 0; j < 4; ++j) {
      e[m][j] = (acc[m][j] + cl[m * 16 + h * 4 + j]) * 0.03125f;
      cmax = fmaxf(cmax, e[m][j]);
    }
  cmax = fmaxf(cmax, __shfl_xor(cmax, 16, 64));
  cmax = fmaxf(cmax, __shfl_xor(cmax, 32, 64));
  float ssum = 0.f;
#pragma unroll
  for (int m = 0; m < 4; ++m)
#pragma unroll
    for (int j = 0; j < 4; ++j) { e[m][j] = expf(e[m][j] - cmax); ssum += e[m][j]; }
  ssum += __shfl_xor(ssum, 16, 64);
  ssum += __shfl_xor(ssum, 32, 64);
  float inv = 1.f / ssum;
  __syncthreads();

  const int n = n0 + wave * 16 + l15;
#pragma unroll
  for (int m = 0; m < 4; ++m)
#pragma unroll
    for (int j = 0; j < 4; ++j) {
      float a = e[m][j] * inv;
      int s = m * 16 + h * 4 + j;
      attn[(size_t)s * N_DET + n] = f2b(a);
      float v = a;
      v += __shfl_xor(v, 1, 64);
      v += __shfl_xor(v, 2, 64);
      v += __shfl_xor(v, 4, 64);
      v += __shfl_xor(v, 8, 64);
      if (l15 == 0) atomicAdd(&cs[s], v);
    }
  __syncthreads();
  if (t < 64) atomicAdd(&colsum[t], cs[t]);
}

// ---------------- mega-setup: transposes + converts + matvecs (+ zero grid-barrier counter) ----------------
__global__ __launch_bounds__(256) void setup_all(
    const float* __restrict__ W_enc, const float* __restrict__ W1, const float* __restrict__ W2,
    bf16* __restrict__ Wenc_t, bf16* __restrict__ W1_t, bf16* __restrict__ W2_t,
    const float* __restrict__ Wh, const float* __restrict__ Wi,
    const float* __restrict__ Wv, const float* __restrict__ Wq, const float* __restrict__ Wk,
    bf16* __restrict__ oWh, bf16* __restrict__ oWi, bf16* __restrict__ oWv,
    bf16* __restrict__ oWq, bf16* __restrict__ oWk,
    const float* __restrict__ bv, const float* __restrict__ bk, const float* __restrict__ bq,
    const float* __restrict__ bi,
    float* __restrict__ bvi, float* __restrict__ wqbk, float* __restrict__ bqk,
    int* __restrict__ bar)
{
  __shared__ float t[32][33];
  int b = blockIdx.x;
  if (b == 0 && threadIdx.x == 0) *bar = 0;
  if (b < 4352) {
    const float* W; bf16* Wt; int K, N, bx, by;
    if (b < 256)       { W = W_enc; Wt = Wenc_t; K = DIN;  N = DD; bx = b & 31;  by = b >> 5; }
    else if (b < 2304) { int r = b - 256;  W = W1; Wt = W1_t; K = DD;  N = HH; bx = r & 63; by = r >> 6; }
    else               { int r = b - 2304; W = W2; Wt = W2_t; K = HH;  N = DD; bx = r & 31; by = r >> 5; }
    int n0 = bx * 32, k0 = by * 32;
    int tx = threadIdx.x & 31, ty = threadIdx.x >> 5;
    for (int r = ty; r < 32; r += 8)
      t[r][tx] = W[(size_t)(k0 + r) * N + n0 + tx];
    __syncthreads();
    for (int r = ty; r < 32; r += 8)
      Wt[(size_t)(n0 + r) * K + k0 + tx] = f2b(t[tx][r]);
  } else if (b < 13568) {
    int cb = b - 4352;
    const float* src; bf16* dst; int base;
    if      (cb < 3072) { src = Wh; dst = oWh; base = cb; }
    else if (cb < 6144) { src = Wi; dst = oWi; base = cb - 3072; }
    else if (cb < 7168) { src = Wv; dst = oWv; base = cb - 6144; }
    else if (cb < 8192) { src = Wq; dst = oWq; base = cb - 7168; }
    else                { src = Wk; dst = oWk; base = cb - 8192; }
    int i = (base * 256 + threadIdx.x) * 4;
    float4 v = *(const float4*)(src + i);
    bf16 o[4] = {f2b(v.x), f2b(v.y), f2b(v.z), f2b(v.w)};
    *(ushort4*)(dst + i) = *(const ushort4*)o;
  } else {
    int row = (b - 13568) * 4 + (threadIdx.x >> 6);
    int lane = threadIdx.x & 63;
    const float* w; const float* vec; float s0; float* out; int idx;
    if (row < 3072)      { idx = row;        w = Wi + (size_t)idx * DD; vec = bv; s0 = bi[idx]; out = bvi; }
    else if (row < 4096) { idx = row - 3072; w = Wq + (size_t)idx * DD; vec = bk; s0 = 0.f;     out = wqbk; }
    else                 { idx = row - 4096; w = Wk + (size_t)idx * DD; vec = bq; s0 = 0.f;     out = bqk; }
    float s = 0.f;
#pragma unroll
    for (int c = 0; c < 4; ++c) {
      float4 wv = *(const float4*)(w + c * 256 + lane * 4);
      float4 bb = *(const float4*)(vec + c * 256 + lane * 4);
      s += wv.x * bb.x + wv.y * bb.y + wv.z * bb.z + wv.w * bb.w;
    }
    for (int o = 32; o > 0; o >>= 1) s += __shfl_down(s, o, 64);
    if (lane == 0) out[idx] = s0 + s;
  }
}

// ---------------- ln_stats: per-row mu/rstd of x_pre (wave per row) ----------------
__global__ __launch_bounds__(256) void ln_stats(const bf16* __restrict__ x_pre,
                                                float2* __restrict__ stats)
{
  int row = blockIdx.x * 4 + (threadIdx.x >> 6);
  int lane = threadIdx.x & 63;
  const bf16* p = x_pre + (size_t)row * DD + lane * 16;
  s16x8 v0 = *(const s16x8*)p;
  s16x8 v1 = *(const s16x8*)(p + 8);
  float s = 0.f, sq = 0.f;
#pragma unroll
  for (int j = 0; j < 8; ++j) {
    float a = bits2f(v0[j]), b = bits2f(v1[j]);
    s += a + b; sq += a * a + b * b;
  }
  for (int o = 32; o > 0; o >>= 1) { s += __shfl_down(s, o, 64); sq += __shfl_down(sq, o, 64); }
  if (lane == 0) {
    float mu = s * (1.f / DD);
    float var = sq * (1.f / DD) - mu * mu;
    stats[row] = make_float2(mu, rsqrtf(var + 1e-5f));
  }
}

// ---------------- norm_transpose: x = LN(x_pre) and xT = x^T, 64x64 tiles (pad 70) ----------------
__global__ __launch_bounds__(256) void norm_transpose(const bf16* __restrict__ x_pre,
    const float2* __restrict__ stats, bf16* __restrict__ x, bf16* __restrict__ xT)
{
  __shared__ bf16 t[64][70];
  int n0 = blockIdx.x * 64, d0 = blockIdx.y * 64;
  int r = threadIdx.x >> 2, c = (threadIdx.x & 3) * 16;
  float2 st = stats[n0 + r];
  s16x8 v0 = *(const s16x8*)&x_pre[(size_t)(n0 + r) * DD + d0 + c];
  s16x8 v1 = *(const s16x8*)&x_pre[(size_t)(n0 + r) * DD + d0 + c + 8];
  bf16 o16[16];
#pragma unroll
  for (int j = 0; j < 8; ++j) {
    o16[j]     = f2b((bits2f(v0[j]) - st.x) * st.y);
    o16[8 + j] = f2b((bits2f(v1[j]) - st.x) * st.y);
  }
  *(s16x8*)&x[(size_t)(n0 + r) * DD + d0 + c]     = *(const s16x8*)&o16[0];
  *(s16x8*)&x[(size_t)(n0 + r) * DD + d0 + c + 8] = *(const s16x8*)&o16[8];
#pragma unroll
  for (int j = 0; j < 16; ++j) t[c + j][r] = o16[j];
  __syncthreads();
  bf16 o[16];
#pragma unroll
  for (int j = 0; j < 16; ++j) o[j] = t[r][c + j];
  *(s16x8*)&xT[(size_t)(d0 + r) * N_DET + n0 + c]     = *(const s16x8*)&o[0];
  *(s16x8*)&xT[(size_t)(d0 + r) * N_DET + n0 + c + 8] = *(const s16x8*)&o[8];
}

// ---------------- fused sim ----------------
__global__ __launch_bounds__(256) void sim_fused(const float* __restrict__ prevs,
    const float* __restrict__ slots, float* __restrict__ simout)
{
  __shared__ float ar[1024];
  __shared__ float lq[4];
  int i = blockIdx.x, t = threadIdx.x;
  float v[4], sq = 0.f;
#pragma unroll
  for (int j = 0; j < 4; j++) { v[j] = prevs[(size_t)i * DD + t + j * 256]; sq += v[j] * v[j]; }
  for (int o = 32; o > 0; o >>= 1) sq += __shfl_down(sq, o, 64);
  int w = t >> 6;
  if ((t & 63) == 0) lq[w] = sq;
  __syncthreads();
  sq = lq[0] + lq[1] + lq[2] + lq[3];
  float sc = 1.f / (sqrtf(sq) + 1e-8f);
#pragma unroll
  for (int j = 0; j < 4; j++) ar[t + j * 256] = v[j] * sc;
  __syncthreads();

  int jr = t >> 2, g = t & 3;
  float dot = 0.f, ss = 0.f;
  for (int d = g; d < 1024; d += 4) {
    float b = slots[(size_t)jr * DD + d];
    dot += ar[d] * b; ss += b * b;
  }
  dot += __shfl_xor(dot, 1, 64); ss += __shfl_xor(ss, 1, 64);
  dot += __shfl_xor(dot, 2, 64); ss += __shfl_xor(ss, 2, 64);
  if (g == 0) simout[i * 64 + jr] = dot / (sqrtf(ss) + 1e-8f);
}

__global__ void match_kernel(const float* __restrict__ sim, float* __restrict__ outm)
{
  __shared__ float m[64];
  __shared__ int idx[64];
  __shared__ int order[64];
  __shared__ int used[64];
  int i = threadIdx.x;
  float best = -1e30f; int bj = 0;
  for (int j = 0; j < 64; j++) {
    float v = sim[i * 64 + j];
    if (v > best) { best = v; bj = j; }
  }
  m[i] = best; idx[i] = bj; used[i] = 0;
  __syncthreads();
  int cnt = 0;
  for (int j = 0; j < 64; j++) {
    float mj = m[j];
    if (mj > best || (mj == best && j < i)) cnt++;
  }
  order[cnt] = i;
  __syncthreads();
  if (i == 0) {
    for (int r = 0; r < 64; r++) {
      int ii = order[r];
      int j = idx[ii];
      bool ok = (!used[j]) && (m[ii] > 0.3f);
      outm[ii] = ok ? (float)j : -1.0f;
      if (ok) used[j] = 1;
    }
  }
}

// ---------------- workspace layout (bytes) ----------------
static constexpr size_t OFF_XPRE = 0;
static constexpr size_t OFF_ATT  = 0;                      // attn bf16 2MB
static constexpr size_t OFF_PA   = (size_t)4  << 20;       // updates/W2 partials 4MB
static constexpr size_t OFF_P0   = (size_t)8  << 20;       // dual p0 768KB
static constexpr size_t OFF_P1   = (size_t)10 << 20;       // dual p1 768KB
static constexpr size_t OFF_WET  = (size_t)32 << 20;
static constexpr size_t OFF_WQKT = OFF_WET + ((size_t)512 << 10);
static constexpr size_t OFF_W1T  = OFF_WQKT + ((size_t)2 << 20);
static constexpr size_t OFF_W2T  = OFF_W1T + ((size_t)4 << 20);
static constexpr size_t OFF_WHB  = OFF_W2T + ((size_t)4 << 20);
static constexpr size_t OFF_WVIT = OFF_WHB + ((size_t)6 << 20);
static constexpr size_t OFF_X    = (size_t)60 << 20;
static constexpr size_t OFF_WIB  = OFF_X;                              // setup only
static constexpr size_t OFF_WVB  = OFF_X + ((size_t)6 << 20);
static constexpr size_t OFF_WQB  = OFF_X + ((size_t)8 << 20);
static constexpr size_t OFF_WKB  = OFF_X + ((size_t)10 << 20);
static constexpr size_t OFF_XT   = OFF_X + ((size_t)32 << 20);
static constexpr size_t OFF_SM   = OFF_XT + ((size_t)32 << 20);
static constexpr size_t OFF_SL   = OFF_SM;
static constexpr size_t OFF_SLPB = OFF_SL  + 262144;
static constexpr size_t OFF_LNB  = OFF_SLPB + 131072;
static constexpr size_t OFF_QKB  = OFF_LNB + 131072;
static constexpr size_t OFF_TB   = OFF_QKB + 131072;
static constexpr size_t OFF_HIDB = OFF_TB  + 131072;
static constexpr size_t OFF_PRV  = OFF_HIDB + 262144;
static constexpr size_t OFF_CS   = OFF_PRV + 262144;      // colsum[64], cbuf[64], bar
static constexpr size_t OFF_BVI  = OFF_CS  + 4096;
static constexpr size_t OFF_WQBK = OFF_BVI + 16384;
static constexpr size_t OFF_BQK  = OFF_WQBK + 4096;
static constexpr size_t OFF_STAT = OFF_BQK + 4096;

extern "C" void kernel_launch(void* const* d_in, const int* in_sizes, int n_in,
                              void* d_out, int out_size, void* d_ws, size_t ws_size,
                              hipStream_t stream)
{
  (void)in_sizes; (void)n_in; (void)out_size; (void)ws_size;
  const float* dets_t   = (const float*)d_in[0];
  const float* dets_t1  = (const float*)d_in[1];
  const float* W_enc    = (const float*)d_in[2];
  const float* b_enc    = (const float*)d_in[3];
  const float* Wq       = (const float*)d_in[4];
  const float* bq       = (const float*)d_in[5];
  const float* Wk       = (const float*)d_in[6];
  const float* bk       = (const float*)d_in[7];
  const float* Wv       = (const float*)d_in[8];
  const float* bv       = (const float*)d_in[9];
  const float* Wi       = (const float*)d_in[10];
  const float* Wh       = (const float*)d_in[11];
  const float* bi       = (const float*)d_in[12];
  const float* bh       = (const float*)d_in[13];
  const float* W1       = (const float*)d_in[14];
  const float* b1       = (const float*)d_in[15];
  const float* W2       = (const float*)d_in[16];
  const float* b2       = (const float*)d_in[17];
  const float* slots_mu = (const float*)d_in[18];
  const float* init_noise = (const float*)d_in[19];

  char* ws = (char*)d_ws;
  bf16*  x_pre  = (bf16*)(ws + OFF_XPRE);
  bf16*  attn   = (bf16*)(ws + OFF_ATT);
  float* pA     = (float*)(ws + OFF_PA);
  float* p0     = (float*)(ws + OFF_P0);
  float* p1     = (float*)(ws + OFF_P1);
  bf16*  Wenc_t = (bf16*)(ws + OFF_WET);
  bf16*  Wqk_t  = (bf16*)(ws + OFF_WQKT);
  bf16*  W1_t   = (bf16*)(ws + OFF_W1T);
  bf16*  W2_t   = (bf16*)(ws + OFF_W2T);
  bf16*  Wh_b   = (bf16*)(ws + OFF_WHB);
  bf16*  Wvit   = (bf16*)(ws + OFF_WVIT);
  bf16*  Wi_b   = (bf16*)(ws + OFF_WIB);
  bf16*  Wv_bf  = (bf16*)(ws + OFF_WVB);
  bf16*  Wq_bf  = (bf16*)(ws + OFF_WQB);
  bf16*  Wk_bf  = (bf16*)(ws + OFF_WKB);
  bf16*  x      = (bf16*)(ws + OFF_X);
  bf16*  xT     = (bf16*)(ws + OFF_XT);
  float* slots  = (float*)(ws + OFF_SL);
  bf16*  slotspb= (bf16*)(ws + OFF_SLPB);
  bf16*  lnb    = (bf16*)(ws + OFF_LNB);
  bf16*  qkb    = (bf16*)(ws + OFF_QKB);
  bf16*  tb     = (bf16*)(ws + OFF_TB);
  bf16*  hidb   = (bf16*)(ws + OFF_HIDB);
  float* prevs  = (float*)(ws + OFF_PRV);
  float* colsum = (float*)(ws + OFF_CS);
  float* cbuf   = colsum + 64;
  int*   bar    = (int*)(colsum + 128);
  float* bvi    = (float*)(ws + OFF_BVI);
  float* wqbk   = (float*)(ws + OFF_WQBK);
  float* bqk    = (float*)(ws + OFF_BQK);
  float2* stats = (float2*)(ws + OFF_STAT);

  // ---- setup (2 dispatches; also zeroes grid-barrier counter) ----
  setup_all<<<14848, 256, 0, stream>>>(W_enc, W1, W2, Wenc_t, W1_t, W2_t,
                                       Wh, Wi, Wv, Wq, Wk, Wh_b, Wi_b, Wv_bf, Wq_bf, Wk_bf,
                                       bv, bk, bq, bi, bvi, wqbk, bqk, bar);
  gemm_setup_pair<<<256, 256, 0, stream>>>(Wi_b, Wv_bf, Wvit, Wk_bf, Wq_bf, Wqk_t);

  int coopj = 0;
  auto frame = [&](const float* dets, bool first) {
    gemm_enc<<<1024, 256, 0, stream>>>(dets, Wenc_t, b_enc, x_pre, N_DET, DD, DIN);
    ln_stats<<<4096, 256, 0, stream>>>(x_pre, stats);
    norm_transpose<<<dim3(256, 16), 256, 0, stream>>>(x_pre, stats, x, xT);
    if (first) {
      slots_init_ln<<<64, 256, 0, stream>>>(slots_mu, init_noise, slots, slotspb, lnb, wqbk, cbuf, colsum);
      gemm_skinny_e<1><<<dim3(16, 1), 256, 0, stream>>>(lnb, Wqk_t, nullptr, qkb, bqk, DD, DD, DD);
    }
    // frame 2: prior frame's last iter_chain produced lnb/slotspb/cbuf/colsum AND qkb
    for (int it = 0; it < 3; ++it) {
      qk_softmax<<<256, 256, 0, stream>>>(qkb, x, cbuf, attn, colsum);
      gemm_skinny_e<0><<<dim3(16, 16), 256, 0, stream>>>(attn, xT, pA, nullptr, nullptr, DD, N_DET, 1024);
      int save = (first && it == 2) ? 1 : 0;
      iter_chain<<<CHAIN_BLOCKS, 256, 0, stream>>>(pA, colsum, cbuf, tb, Wvit, Wh_b, p0, p1,
                                                   bvi, bh, slots, lnb, W1_t, b1, hidb,
                                                   W2_t, pA, b2, slotspb, wqbk,
                                                   Wqk_t, bqk, qkb, prevs, save, bar, coopj * 6);
      ++coopj;
    }
  };

  frame(dets_t, true);
  frame(dets_t1, false);

  float* outf = (float*)d_out;
  sim_fused<<<KSLOT, 256, 0, stream>>>(prevs, slots, outf + 64);
  match_kernel<<<1, 64, 0, stream>>>(outf + 64, outf);
}

// Round 17
// 635.883 us; speedup vs baseline: 1.3270x; 1.3270x over previous
//
#include <hip/hip_runtime.h>
#include <hip/hip_bf16.h>
#include <type_traits>

typedef __hip_bfloat16 bf16;
typedef __attribute__((ext_vector_type(8))) short s16x8;   // 8 bf16 (4 VGPRs)
typedef __attribute__((ext_vector_type(4))) float f32x4;

#define N_DET 16384
#define DIN   256
#define DD    1024
#define KSLOT 64
#define HH    2048
#define TD    3072

__device__ __forceinline__ float b2f(bf16 x){ return __bfloat162float(x); }
__device__ __forceinline__ bf16  f2b(float x){ return __float2bfloat16(x); }
__device__ __forceinline__ float bits2f(short u){ return __uint_as_float(((unsigned)(unsigned short)u) << 16); }

__device__ __forceinline__ void gload_lds16(const void* g, void* l) {
  __builtin_amdgcn_global_load_lds(
      (const __attribute__((address_space(1))) unsigned int*)g,
      (__attribute__((address_space(3))) unsigned int*)l, 16, 0, 0);
}

// ================= big-GEMM compute: 128x128 tile, BK=64, XOR-swizzled LDS (proven) =================
__device__ __forceinline__ void big_compute(bf16* As, bf16* Bs,
    const bf16* __restrict__ Ap, const bf16* __restrict__ Bp, int K, f32x4 acc[4][4])
{
  const int tid = threadIdx.x;
  const int lane = tid & 63, wave = tid >> 6;
  const int wr = wave >> 1, wc = wave & 1;
  const int l15 = lane & 15, h = lane >> 4;
  const int rr = tid >> 3;
  const int qs = ((tid & 7) ^ (rr & 7)) * 8;

#pragma unroll
  for (int m = 0; m < 4; ++m)
#pragma unroll
    for (int n = 0; n < 4; ++n) acc[m][n] = {0.f, 0.f, 0.f, 0.f};

  for (int k0 = 0; k0 < K; k0 += 64) {
    __syncthreads();
#pragma unroll
    for (int g = 0; g < 4; ++g)
      gload_lds16(Ap + (size_t)(g * 32 + rr) * K + k0 + qs,
                  As + ((size_t)g * 256 + wave * 64) * 8);
#pragma unroll
    for (int g = 0; g < 4; ++g)
      gload_lds16(Bp + (size_t)(g * 32 + rr) * K + k0 + qs,
                  Bs + ((size_t)g * 256 + wave * 64) * 8);
    __syncthreads();

#pragma unroll
    for (int ks = 0; ks < 2; ++ks) {
      s16x8 af[4], bfr[4];
#pragma unroll
      for (int m = 0; m < 4; ++m) {
        int row = wr * 64 + m * 16 + l15;
        af[m] = *(const s16x8*)&As[row * 64 + (((ks * 4 + h) ^ (l15 & 7)) * 8)];
      }
#pragma unroll
      for (int n = 0; n < 4; ++n) {
        int row = wc * 64 + n * 16 + l15;
        bfr[n] = *(const s16x8*)&Bs[row * 64 + (((ks * 4 + h) ^ (l15 & 7)) * 8)];
      }
#pragma unroll
      for (int m = 0; m < 4; ++m)
#pragma unroll
        for (int n = 0; n < 4; ++n)
          acc[m][n] = __builtin_amdgcn_mfma_f32_16x16x32_bf16(af[m], bfr[n], acc[m][n], 0, 0, 0);
    }
  }
}

__device__ __forceinline__ void big_epilogue(int bm, int bn,
    const float* __restrict__ bias, bf16* __restrict__ C, int N, f32x4 acc[4][4])
{
  const int lane = threadIdx.x & 63, wave = threadIdx.x >> 6;
  const int wr = wave >> 1, wc = wave & 1;
#pragma unroll
  for (int m = 0; m < 4; ++m)
#pragma unroll
    for (int n = 0; n < 4; ++n) {
      int col = bn + wc * 64 + n * 16 + (lane & 15);
      float bv = bias ? bias[col] : 0.f;
#pragma unroll
      for (int j = 0; j < 4; ++j) {
        int row = bm + wr * 64 + m * 16 + (lane >> 4) * 4 + j;
        C[(size_t)row * N + col] = f2b(acc[m][n][j] + bv);
      }
    }
}

__device__ __forceinline__ void big_gemm_body(int wg, int nct,
    const bf16* __restrict__ A, const bf16* __restrict__ Bt,
    const float* __restrict__ bias, bf16* __restrict__ C, int N, int K,
    bf16* As, bf16* Bs)
{
  const int bn = (wg % nct) * 128;
  const int bm = (wg / nct) * 128;
  f32x4 acc[4][4];
  big_compute(As, Bs, A + (size_t)bm * K, Bt + (size_t)bn * K, K, acc);
  big_epilogue(bm, bn, bias, C, N, acc);
}

// ---------------- enc GEMM: A f32 converted in-reg (proven R14 form, BK=64) ----------------
__global__ __launch_bounds__(256) void gemm_enc(
    const float* __restrict__ A, const bf16* __restrict__ Bt,
    const float* __restrict__ bias, bf16* __restrict__ C, int M, int N, int K)
{
  const int nct = N >> 7;
  const int chunk = gridDim.x >> 3;
  const int wg = (blockIdx.x & 7) * chunk + (blockIdx.x >> 3);
  const int bn = (wg % nct) * 128;
  const int bm = (wg / nct) * 128;

  __shared__ bf16 As[128 * 64];
  __shared__ bf16 Bs[128 * 64];
  const int tid = threadIdx.x;
  const int lane = tid & 63, wave = tid >> 6;
  const int l15 = lane & 15, h = lane >> 4;
  const int wr = wave >> 1, wc = wave & 1;
  const int rr = tid >> 3;
  const int qs = ((tid & 7) ^ (rr & 7)) * 8;

  f32x4 acc[4][4];
#pragma unroll
  for (int m = 0; m < 4; ++m)
#pragma unroll
    for (int n = 0; n < 4; ++n) acc[m][n] = {0.f, 0.f, 0.f, 0.f};

  for (int k0 = 0; k0 < K; k0 += 64) {
    __syncthreads();
#pragma unroll
    for (int g = 0; g < 4; ++g) {
      const float* src = A + (size_t)(bm + g * 32 + rr) * K + k0 + qs;
      float4 f0 = *(const float4*)src;
      float4 f1 = *(const float4*)(src + 4);
      bf16 pk[8] = {f2b(f0.x), f2b(f0.y), f2b(f0.z), f2b(f0.w),
                    f2b(f1.x), f2b(f1.y), f2b(f1.z), f2b(f1.w)};
      *(s16x8*)&As[g * 2048 + tid * 8] = *(const s16x8*)pk;
    }
#pragma unroll
    for (int g = 0; g < 4; ++g)
      gload_lds16(Bt + (size_t)(bn + g * 32 + rr) * K + k0 + qs,
                  Bs + ((size_t)g * 256 + wave * 64) * 8);
    __syncthreads();

#pragma unroll
    for (int ks = 0; ks < 2; ++ks) {
      s16x8 af[4], bfr[4];
#pragma unroll
      for (int m = 0; m < 4; ++m) {
        int row = wr * 64 + m * 16 + l15;
        af[m] = *(const s16x8*)&As[row * 64 + (((ks * 4 + h) ^ (l15 & 7)) * 8)];
      }
#pragma unroll
      for (int n = 0; n < 4; ++n) {
        int row = wc * 64 + n * 16 + l15;
        bfr[n] = *(const s16x8*)&Bs[row * 64 + (((ks * 4 + h) ^ (l15 & 7)) * 8)];
      }
#pragma unroll
      for (int m = 0; m < 4; ++m)
#pragma unroll
        for (int n = 0; n < 4; ++n)
          acc[m][n] = __builtin_amdgcn_mfma_f32_16x16x32_bf16(af[m], bfr[n], acc[m][n], 0, 0, 0);
    }
  }
  big_epilogue(bm, bn, bias, C, N, acc);
}

// ---------------- merged setup GEMMs ----------------
__global__ __launch_bounds__(256) void gemm_setup_pair(
    const bf16* __restrict__ Wi_b, const bf16* __restrict__ Wv_bf, bf16* __restrict__ Wvit,
    const bf16* __restrict__ Wk_bf, const bf16* __restrict__ Wq_bf, bf16* __restrict__ Wqk_t)
{
  __shared__ bf16 As[128 * 64];
  __shared__ bf16 Bs[128 * 64];
  if (blockIdx.x < 192) {
    int bid = blockIdx.x;
    int wg = (bid & 7) * 24 + (bid >> 3);
    big_gemm_body(wg, 8, Wi_b, Wv_bf, nullptr, Wvit, DD, DD, As, Bs);
  } else {
    int bid = blockIdx.x - 192;
    int wg = (bid & 7) * 8 + (bid >> 3);
    big_gemm_body(wg, 8, Wk_bf, Wq_bf, nullptr, Wqk_t, DD, DD, As, Bs);
  }
}

// ================= skinny split-K MFMA: proven layout, BK=256/barrier =================
__device__ __forceinline__ void skinny_compute(bf16* As, bf16* Bs,
    const bf16* __restrict__ A, const bf16* __restrict__ Bt,
    int K, int Kc, int n0, int kb0, f32x4 acc[4])
{
  const int tid = threadIdx.x;
  const int lane = tid & 63, wave = tid >> 6;
  const int rem = wave * 64 + lane;
  const int r = rem >> 2, q = rem & 3;
  const int l15 = lane & 15, h = lane >> 4;

#pragma unroll
  for (int m = 0; m < 4; ++m) acc[m] = {0.f, 0.f, 0.f, 0.f};

  for (int kb = kb0; kb < kb0 + Kc; kb += 256) {
    __syncthreads();
#pragma unroll
    for (int half = 0; half < 2; ++half) {
#pragma unroll
      for (int g = 0; g < 4; ++g)
        gload_lds16(A + (size_t)r * K + kb + half * 128 + g * 32 + q * 8,
                    As + (size_t)half * 8192 + ((size_t)g * 256 + wave * 64) * 8);
#pragma unroll
      for (int g = 0; g < 4; ++g)
        gload_lds16(Bt + (size_t)(n0 + r) * K + kb + half * 128 + g * 32 + q * 8,
                    Bs + (size_t)half * 8192 + ((size_t)g * 256 + wave * 64) * 8);
    }
    __syncthreads();

#pragma unroll
    for (int half = 0; half < 2; ++half)
#pragma unroll
      for (int ks = 0; ks < 4; ++ks) {
        s16x8 bfr = *(const s16x8*)&Bs[half * 8192 + (ks * 64 + wave * 16 + l15) * 32 + h * 8];
#pragma unroll
        for (int m = 0; m < 4; ++m) {
          s16x8 af = *(const s16x8*)&As[half * 8192 + (ks * 64 + m * 16 + l15) * 32 + h * 8];
          acc[m] = __builtin_amdgcn_mfma_f32_16x16x32_bf16(af, bfr, acc[m], 0, 0, 0);
        }
      }
  }
}

// EPI: 0 = f32 partial @ row blockIdx.y*64; 1 = bf16 + bias; 2 = bf16 + bias + relu
template<int EPI>
__global__ __launch_bounds__(256) void gemm_skinny_e(
    const bf16* __restrict__ A, const bf16* __restrict__ Bt,
    float* __restrict__ pbuf, bf16* __restrict__ outb,
    const float* __restrict__ bias, int N, int K, int Kc)
{
  __shared__ bf16 As[2 * 4 * 64 * 32];
  __shared__ bf16 Bs[2 * 4 * 64 * 32];
  f32x4 acc[4];
  skinny_compute(As, Bs, A, Bt, K, Kc, blockIdx.x * 64, blockIdx.y * Kc, acc);

  const int lane = threadIdx.x & 63, wave = threadIdx.x >> 6;
  const int l15 = lane & 15, h = lane >> 4;
#pragma unroll
  for (int m = 0; m < 4; ++m)
#pragma unroll
    for (int j = 0; j < 4; ++j) {
      int row = m * 16 + h * 4 + j;
      int col = blockIdx.x * 64 + wave * 16 + l15;
      if (EPI == 0) {
        pbuf[((size_t)(blockIdx.y * 64) + row) * N + col] = acc[m][j];
      } else {
        float v = acc[m][j] + bias[col];
        if (EPI == 2) v = fmaxf(v, 0.f);
        outb[(size_t)row * N + col] = f2b(v);
      }
    }
}

// dual: z=0 -> A0@B0 -> p0, z=1 -> A1@B1 -> p1 (single pass Kc=K)
__global__ __launch_bounds__(256) void gemm_skinny_dual(
    const bf16* __restrict__ A0, const bf16* __restrict__ A1,
    const bf16* __restrict__ B0, const bf16* __restrict__ B1,
    float* __restrict__ p0, float* __restrict__ p1, int N, int K, int Kc)
{
  __shared__ bf16 As[2 * 4 * 64 * 32];
  __shared__ bf16 Bs[2 * 4 * 64 * 32];
  const bf16* A = blockIdx.z ? A1 : A0;
  const bf16* B = blockIdx.z ? B1 : B0;
  float* p = blockIdx.z ? p1 : p0;

  f32x4 acc[4];
  skinny_compute(As, Bs, A, B, K, Kc, blockIdx.x * 64, blockIdx.y * Kc, acc);

  const int lane = threadIdx.x & 63, wave = threadIdx.x >> 6;
  const int l15 = lane & 15, h = lane >> 4;
#pragma unroll
  for (int m = 0; m < 4; ++m)
#pragma unroll
    for (int j = 0; j < 4; ++j) {
      int row = m * 16 + h * 4 + j;
      int col = blockIdx.x * 64 + wave * 16 + l15;
      p[((size_t)(blockIdx.y * 64) + row) * N + col] = acc[m][j];
    }
}

// ---------------- block LN helper; optional: cbuf[row]=ln_row·wqbk, colsum[row]=0 ----------------
__device__ __forceinline__ void block_ln_store(float v[4], float s, float sq,
    bf16* __restrict__ out, int row,
    const float* __restrict__ wqbk, float* __restrict__ cbuf, float* __restrict__ colsum)
{
  for (int o = 32; o > 0; o >>= 1) { s += __shfl_down(s, o, 64); sq += __shfl_down(sq, o, 64); }
  __shared__ float ls[4], lq[4];
  int w = threadIdx.x >> 6;
  if ((threadIdx.x & 63) == 0) { ls[w] = s; lq[w] = sq; }
  __syncthreads();
  s  = ls[0] + ls[1] + ls[2] + ls[3];
  sq = lq[0] + lq[1] + lq[2] + lq[3];
  float mu = s * (1.f / DD);
  float var = sq * (1.f / DD) - mu * mu;
  float rstd = rsqrtf(var + 1e-5f);
#pragma unroll
  for (int j = 0; j < 4; j++)
    out[(size_t)row * DD + threadIdx.x + j * 256] = f2b((v[j] - mu) * rstd);
  if (wqbk) {
    float dot = 0.f;
#pragma unroll
    for (int j = 0; j < 4; j++) dot += (v[j] - mu) * rstd * wqbk[threadIdx.x + j * 256];
    for (int o = 32; o > 0; o >>= 1) dot += __shfl_down(dot, o, 64);
    __syncthreads();
    if ((threadIdx.x & 63) == 0) ls[w] = dot;
    __syncthreads();
    if (threadIdx.x == 0) { cbuf[row] = ls[0] + ls[1] + ls[2] + ls[3]; colsum[row] = 0.f; }
  }
}

// ---------------- fused GRU reduce + LN (bvi = bi + Wi@bv folded in) ----------------
__global__ __launch_bounds__(256) void gru_reduce_ln(const float* __restrict__ pA,
    const float* __restrict__ pB, const float* __restrict__ bvi,
    const float* __restrict__ bh, float* __restrict__ slots, bf16* __restrict__ lnb)
{
  int s = blockIdx.x, t = threadIdx.x;
  float v[4], sum = 0.f, sq = 0.f;
#pragma unroll
  for (int j = 0; j < 4; ++j) {
    int d = t + j * 256;
    const float* a = pA + (size_t)s * TD;
    const float* b = pB + (size_t)s * TD;
    float ir = bvi[d] + a[d], iz = bvi[1024 + d] + a[1024 + d], in_ = bvi[2048 + d] + a[2048 + d];
    float hr = bh[d] + b[d], hz = bh[1024 + d] + b[1024 + d], hnn = bh[2048 + d] + b[2048 + d];
    float r = 1.f / (1.f + expf(-(ir + hr)));
    float z = 1.f / (1.f + expf(-(iz + hz)));
    float nn = tanhf(in_ + r * hnn);
    float h = slots[(size_t)s * DD + d];
    float hv = (1.f - z) * nn + z * h;
    slots[(size_t)s * DD + d] = hv;
    v[j] = hv; sum += hv; sq += hv * hv;
  }
  block_ln_store(v, sum, sq, lnb, s, nullptr, nullptr, nullptr);
}

// ---------------- fused MLP-out reduce + resid + LN + bf16 prev-copy + cbuf/colsum prep ----------------
template<int SK>
__global__ __launch_bounds__(256) void mlp2_reduce_ln(const float* __restrict__ pbuf,
    const float* __restrict__ bias, float* __restrict__ slots,
    bf16* __restrict__ slotspb, bf16* __restrict__ lnb,
    const float* __restrict__ wqbk, float* __restrict__ cbuf, float* __restrict__ colsum,
    float* __restrict__ prevs)
{
  int s = blockIdx.x, t = threadIdx.x;
  float v[4], sum = 0.f, sq = 0.f;
#pragma unroll
  for (int j = 0; j < 4; ++j) {
    int d = t + j * 256;
    float x = bias[d] + slots[(size_t)s * DD + d];
#pragma unroll
    for (int sk = 0; sk < SK; ++sk) x += pbuf[(size_t)(sk * 64 + s) * DD + d];
    slots[(size_t)s * DD + d] = x;
    slotspb[(size_t)s * DD + d] = f2b(x);
    if (prevs) prevs[(size_t)s * DD + d] = x;
    v[j] = x; sum += x; sq += x * x;
  }
  block_ln_store(v, sum, sq, lnb, s, wqbk, cbuf, colsum);
}

// ---------------- slots init (frame 1 only) ----------------
__global__ __launch_bounds__(256) void slots_init_ln(const float* __restrict__ mu,
    const float* __restrict__ noise, float* __restrict__ slots,
    bf16* __restrict__ slotspb, bf16* __restrict__ lnb,
    const float* __restrict__ wqbk, float* __restrict__ cbuf, float* __restrict__ colsum)
{
  int s = blockIdx.x, t = threadIdx.x;
  float v[4], sum = 0.f, sq = 0.f;
#pragma unroll
  for (int j = 0; j < 4; ++j) {
    int d = t + j * 256;
    float x = mu[d] + noise[(size_t)s * DD + d];
    slots[(size_t)s * DD + d] = x;
    slotspb[(size_t)s * DD + d] = f2b(x);
    v[j] = x; sum += x; sq += x * x;
  }
  block_ln_store(v, sum, sq, lnb, s, wqbk, cbuf, colsum);
}

// ---------------- fused QK^T(+c) + softmax(axis=slots) + colsum — proven layout, BK=256/barrier ----------------
__global__ __launch_bounds__(256) void qk_softmax(const bf16* __restrict__ qkb,
    const bf16* __restrict__ x, const float* __restrict__ cbuf,
    bf16* __restrict__ attn, float* __restrict__ colsum)
{
  __shared__ bf16 Qs[4 * 64 * 64];
  __shared__ bf16 Ks[4 * 64 * 64];
  __shared__ float cs[64], cl[64];
  const int t = threadIdx.x, lane = t & 63, wave = t >> 6;
  const int n0 = blockIdx.x * 64;
  const int l15 = lane & 15, h = lane >> 4;
  if (t < 64) { cs[t] = 0.f; cl[t] = cbuf[t]; }

  f32x4 acc[4];
#pragma unroll
  for (int m = 0; m < 4; ++m) acc[m] = {0.f, 0.f, 0.f, 0.f};

  for (int k0 = 0; k0 < DD; k0 += 256) {
    __syncthreads();
#pragma unroll
    for (int half = 0; half < 4; ++half) {
#pragma unroll
      for (int c = 0; c < 2; ++c) {
        int i = c * 256 + t;
        int r = i >> 3, q8 = i & 7;
        gload_lds16(qkb + (size_t)r * DD + k0 + half * 64 + q8 * 8,
                    Qs + (size_t)half * 4096 + ((size_t)c * 256 + wave * 64) * 8);
      }
#pragma unroll
      for (int c = 0; c < 2; ++c) {
        int i = c * 256 + t;
        int r = i >> 3, q8 = i & 7;
        gload_lds16(x + (size_t)(n0 + r) * DD + k0 + half * 64 + q8 * 8,
                    Ks + (size_t)half * 4096 + ((size_t)c * 256 + wave * 64) * 8);
      }
    }
    __syncthreads();

#pragma unroll
    for (int half = 0; half < 4; ++half)
#pragma unroll
      for (int ks = 0; ks < 2; ++ks) {
        s16x8 bfr = *(const s16x8*)&Ks[half * 4096 + (wave * 16 + l15) * 64 + ks * 32 + h * 8];
#pragma unroll
        for (int m = 0; m < 4; ++m) {
          s16x8 af = *(const s16x8*)&Qs[half * 4096 + (m * 16 + l15) * 64 + ks * 32 + h * 8];
          acc[m] = __builtin_amdgcn_mfma_f32_16x16x32_bf16(af, bfr, acc[m], 0, 0, 0);
        }
      }
  }

  float e[4][4];
  float cmax = -1e30f;
#pragma unroll
  for (int m = 0; m < 4; ++m)
#pragma unroll
    for (int j = 0; j < 4; ++j) {
      e[m][j] = (acc[m][j] + cl[m * 16 + h * 4 + j]) * 0.03125f;
      cmax = fmaxf(cmax, e[m][j]);
    }
  cmax = fmaxf(cmax, __shfl_xor(cmax, 16, 64));
  cmax = fmaxf(cmax, __shfl_xor(cmax, 32, 64));
  float ssum = 0.f;
#pragma unroll
  for (int m = 0; m < 4; ++m)
#pragma unroll
    for (int j = 0; j < 4; ++j) { e[m][j] = expf(e[m][j] - cmax); ssum += e[m][j]; }
  ssum += __shfl_xor(ssum, 16, 64);
  ssum += __shfl_xor(ssum, 32, 64);
  float inv = 1.f / ssum;
  __syncthreads();

  const int n = n0 + wave * 16 + l15;
#pragma unroll
  for (int m = 0; m < 4; ++m)
#pragma unroll
    for (int j = 0; j < 4; ++j) {
      float a = e[m][j] * inv;
      int s = m * 16 + h * 4 + j;
      attn[(size_t)s * N_DET + n] = f2b(a);
      float v = a;
      v += __shfl_xor(v, 1, 64);
      v += __shfl_xor(v, 2, 64);
      v += __shfl_xor(v, 4, 64);
      v += __shfl_xor(v, 8, 64);
      if (l15 == 0) atomicAdd(&cs[s], v);
    }
  __syncthreads();
  if (t < 64) atomicAdd(&colsum[t], cs[t]);
}

// ---------------- t-reduce: tb = (sum_sk partials) / (colsum+eps) -> bf16 ----------------
template<int SK>
__global__ __launch_bounds__(256) void updates_reduce2(const float* __restrict__ pbuf,
    const float* __restrict__ colsum, bf16* __restrict__ tb)
{
  int s = blockIdx.y, d = blockIdx.x * 256 + threadIdx.x;
  float v = 0.f;
#pragma unroll
  for (int sk = 0; sk < SK; ++sk) v += pbuf[(size_t)(sk * 64 + s) * DD + d];
  tb[(size_t)s * DD + d] = f2b(v / (colsum[s] + 1e-8f));
}

// ---------------- mega-setup: transposes (0..4351) + converts (4352..13567) + matvecs (13568..) ----------------
__global__ __launch_bounds__(256) void setup_all(
    const float* __restrict__ W_enc, const float* __restrict__ W1, const float* __restrict__ W2,
    bf16* __restrict__ Wenc_t, bf16* __restrict__ W1_t, bf16* __restrict__ W2_t,
    const float* __restrict__ Wh, const float* __restrict__ Wi,
    const float* __restrict__ Wv, const float* __restrict__ Wq, const float* __restrict__ Wk,
    bf16* __restrict__ oWh, bf16* __restrict__ oWi, bf16* __restrict__ oWv,
    bf16* __restrict__ oWq, bf16* __restrict__ oWk,
    const float* __restrict__ bv, const float* __restrict__ bk, const float* __restrict__ bq,
    const float* __restrict__ bi,
    float* __restrict__ bvi, float* __restrict__ wqbk, float* __restrict__ bqk)
{
  __shared__ float t[32][33];
  int b = blockIdx.x;
  if (b < 4352) {
    const float* W; bf16* Wt; int K, N, bx, by;
    if (b < 256)       { W = W_enc; Wt = Wenc_t; K = DIN;  N = DD; bx = b & 31;  by = b >> 5; }
    else if (b < 2304) { int r = b - 256;  W = W1; Wt = W1_t; K = DD;  N = HH; bx = r & 63; by = r >> 6; }
    else               { int r = b - 2304; W = W2; Wt = W2_t; K = HH;  N = DD; bx = r & 31; by = r >> 5; }
    int n0 = bx * 32, k0 = by * 32;
    int tx = threadIdx.x & 31, ty = threadIdx.x >> 5;
    for (int r = ty; r < 32; r += 8)
      t[r][tx] = W[(size_t)(k0 + r) * N + n0 + tx];
    __syncthreads();
    for (int r = ty; r < 32; r += 8)
      Wt[(size_t)(n0 + r) * K + k0 + tx] = f2b(t[tx][r]);
  } else if (b < 13568) {
    int cb = b - 4352;
    const float* src; bf16* dst; int base;
    if      (cb < 3072) { src = Wh; dst = oWh; base = cb; }
    else if (cb < 6144) { src = Wi; dst = oWi; base = cb - 3072; }
    else if (cb < 7168) { src = Wv; dst = oWv; base = cb - 6144; }
    else if (cb < 8192) { src = Wq; dst = oWq; base = cb - 7168; }
    else                { src = Wk; dst = oWk; base = cb - 8192; }
    int i = (base * 256 + threadIdx.x) * 4;
    float4 v = *(const float4*)(src + i);
    bf16 o[4] = {f2b(v.x), f2b(v.y), f2b(v.z), f2b(v.w)};
    *(ushort4*)(dst + i) = *(const ushort4*)o;
  } else {
    int row = (b - 13568) * 4 + (threadIdx.x >> 6);   // 0..5119
    int lane = threadIdx.x & 63;
    const float* w; const float* vec; float s0; float* out; int idx;
    if (row < 3072)      { idx = row;        w = Wi + (size_t)idx * DD; vec = bv; s0 = bi[idx]; out = bvi; }
    else if (row < 4096) { idx = row - 3072; w = Wq + (size_t)idx * DD; vec = bk; s0 = 0.f;     out = wqbk; }
    else                 { idx = row - 4096; w = Wk + (size_t)idx * DD; vec = bq; s0 = 0.f;     out = bqk; }
    float s = 0.f;
#pragma unroll
    for (int c = 0; c < 4; ++c) {
      float4 wv = *(const float4*)(w + c * 256 + lane * 4);
      float4 bb = *(const float4*)(vec + c * 256 + lane * 4);
      s += wv.x * bb.x + wv.y * bb.y + wv.z * bb.z + wv.w * bb.w;
    }
    for (int o = 32; o > 0; o >>= 1) s += __shfl_down(s, o, 64);
    if (lane == 0) out[idx] = s0 + s;
  }
}

// ---------------- ln_stats: per-row mu/rstd of x_pre (wave per row) ----------------
__global__ __launch_bounds__(256) void ln_stats(const bf16* __restrict__ x_pre,
                                                float2* __restrict__ stats)
{
  int row = blockIdx.x * 4 + (threadIdx.x >> 6);
  int lane = threadIdx.x & 63;
  const bf16* p = x_pre + (size_t)row * DD + lane * 16;
  s16x8 v0 = *(const s16x8*)p;
  s16x8 v1 = *(const s16x8*)(p + 8);
  float s = 0.f, sq = 0.f;
#pragma unroll
  for (int j = 0; j < 8; ++j) {
    float a = bits2f(v0[j]), b = bits2f(v1[j]);
    s += a + b; sq += a * a + b * b;
  }
  for (int o = 32; o > 0; o >>= 1) { s += __shfl_down(s, o, 64); sq += __shfl_down(sq, o, 64); }
  if (lane == 0) {
    float mu = s * (1.f / DD);
    float var = sq * (1.f / DD) - mu * mu;
    stats[row] = make_float2(mu, rsqrtf(var + 1e-5f));
  }
}

// ---------------- norm_transpose: x = LN(x_pre) and xT = x^T, 64x64 tiles (pad 70) ----------------
__global__ __launch_bounds__(256) void norm_transpose(const bf16* __restrict__ x_pre,
    const float2* __restrict__ stats, bf16* __restrict__ x, bf16* __restrict__ xT)
{
  __shared__ bf16 t[64][70];
  int n0 = blockIdx.x * 64, d0 = blockIdx.y * 64;
  int r = threadIdx.x >> 2, c = (threadIdx.x & 3) * 16;
  float2 st = stats[n0 + r];
  s16x8 v0 = *(const s16x8*)&x_pre[(size_t)(n0 + r) * DD + d0 + c];
  s16x8 v1 = *(const s16x8*)&x_pre[(size_t)(n0 + r) * DD + d0 + c + 8];
  bf16 o16[16];
#pragma unroll
  for (int j = 0; j < 8; ++j) {
    o16[j]     = f2b((bits2f(v0[j]) - st.x) * st.y);
    o16[8 + j] = f2b((bits2f(v1[j]) - st.x) * st.y);
  }
  *(s16x8*)&x[(size_t)(n0 + r) * DD + d0 + c]     = *(const s16x8*)&o16[0];
  *(s16x8*)&x[(size_t)(n0 + r) * DD + d0 + c + 8] = *(const s16x8*)&o16[8];
#pragma unroll
  for (int j = 0; j < 16; ++j) t[c + j][r] = o16[j];
  __syncthreads();
  bf16 o[16];
#pragma unroll
  for (int j = 0; j < 16; ++j) o[j] = t[r][c + j];
  *(s16x8*)&xT[(size_t)(d0 + r) * N_DET + n0 + c]     = *(const s16x8*)&o[0];
  *(s16x8*)&xT[(size_t)(d0 + r) * N_DET + n0 + c + 8] = *(const s16x8*)&o[8];
}

// ---------------- fused sim ----------------
__global__ __launch_bounds__(256) void sim_fused(const float* __restrict__ prevs,
    const float* __restrict__ slots, float* __restrict__ simout)
{
  __shared__ float ar[1024];
  __shared__ float lq[4];
  int i = blockIdx.x, t = threadIdx.x;
  float v[4], sq = 0.f;
#pragma unroll
  for (int j = 0; j < 4; j++) { v[j] = prevs[(size_t)i * DD + t + j * 256]; sq += v[j] * v[j]; }
  for (int o = 32; o > 0; o >>= 1) sq += __shfl_down(sq, o, 64);
  int w = t >> 6;
  if ((t & 63) == 0) lq[w] = sq;
  __syncthreads();
  sq = lq[0] + lq[1] + lq[2] + lq[3];
  float sc = 1.f / (sqrtf(sq) + 1e-8f);
#pragma unroll
  for (int j = 0; j < 4; j++) ar[t + j * 256] = v[j] * sc;
  __syncthreads();

  int jr = t >> 2, g = t & 3;
  float dot = 0.f, ss = 0.f;
  for (int d = g; d < 1024; d += 4) {
    float b = slots[(size_t)jr * DD + d];
    dot += ar[d] * b; ss += b * b;
  }
  dot += __shfl_xor(dot, 1, 64); ss += __shfl_xor(ss, 1, 64);
  dot += __shfl_xor(dot, 2, 64); ss += __shfl_xor(ss, 2, 64);
  if (g == 0) simout[i * 64 + jr] = dot / (sqrtf(ss) + 1e-8f);
}

__global__ void match_kernel(const float* __restrict__ sim, float* __restrict__ outm)
{
  __shared__ float m[64];
  __shared__ int idx[64];
  __shared__ int order[64];
  __shared__ int used[64];
  int i = threadIdx.x;
  float best = -1e30f; int bj = 0;
  for (int j = 0; j < 64; j++) {
    float v = sim[i * 64 + j];
    if (v > best) { best = v; bj = j; }
  }
  m[i] = best; idx[i] = bj; used[i] = 0;
  __syncthreads();
  int cnt = 0;
  for (int j = 0; j < 64; j++) {
    float mj = m[j];
    if (mj > best || (mj == best && j < i)) cnt++;
  }
  order[cnt] = i;
  __syncthreads();
  if (i == 0) {
    for (int r = 0; r < 64; r++) {
      int ii = order[r];
      int j = idx[ii];
      bool ok = (!used[j]) && (m[ii] > 0.3f);
      outm[ii] = ok ? (float)j : -1.0f;
      if (ok) used[j] = 1;
    }
  }
}

// ---------------- workspace layout (bytes) ----------------
static constexpr size_t OFF_XPRE = 0;
static constexpr size_t OFF_ATT  = 0;                      // attn bf16 2MB
static constexpr size_t OFF_PA   = (size_t)4  << 20;       // updates/W2 partials 4MB
static constexpr size_t OFF_P0   = (size_t)8  << 20;       // dual p0 768KB
static constexpr size_t OFF_P1   = (size_t)10 << 20;       // dual p1 768KB
static constexpr size_t OFF_WET  = (size_t)32 << 20;
static constexpr size_t OFF_WQKT = OFF_WET + ((size_t)512 << 10);
static constexpr size_t OFF_W1T  = OFF_WQKT + ((size_t)2 << 20);
static constexpr size_t OFF_W2T  = OFF_W1T + ((size_t)4 << 20);
static constexpr size_t OFF_WHB  = OFF_W2T + ((size_t)4 << 20);
static constexpr size_t OFF_WVIT = OFF_WHB + ((size_t)6 << 20);
static constexpr size_t OFF_X    = (size_t)60 << 20;
static constexpr size_t OFF_WIB  = OFF_X;                              // setup only
static constexpr size_t OFF_WVB  = OFF_X + ((size_t)6 << 20);
static constexpr size_t OFF_WQB  = OFF_X + ((size_t)8 << 20);
static constexpr size_t OFF_WKB  = OFF_X + ((size_t)10 << 20);
static constexpr size_t OFF_XT   = OFF_X + ((size_t)32 << 20);
static constexpr size_t OFF_SM   = OFF_XT + ((size_t)32 << 20);
static constexpr size_t OFF_SL   = OFF_SM;
static constexpr size_t OFF_SLPB = OFF_SL  + 262144;
static constexpr size_t OFF_LNB  = OFF_SLPB + 131072;
static constexpr size_t OFF_QKB  = OFF_LNB + 131072;
static constexpr size_t OFF_TB   = OFF_QKB + 131072;
static constexpr size_t OFF_HIDB = OFF_TB  + 131072;
static constexpr size_t OFF_PRV  = OFF_HIDB + 262144;
static constexpr size_t OFF_CS   = OFF_PRV + 262144;
static constexpr size_t OFF_BVI  = OFF_CS  + 4096;
static constexpr size_t OFF_WQBK = OFF_BVI + 16384;
static constexpr size_t OFF_BQK  = OFF_WQBK + 4096;
static constexpr size_t OFF_STAT = OFF_BQK + 4096;

extern "C" void kernel_launch(void* const* d_in, const int* in_sizes, int n_in,
                              void* d_out, int out_size, void* d_ws, size_t ws_size,
                              hipStream_t stream)
{
  (void)in_sizes; (void)n_in; (void)out_size; (void)ws_size;
  const float* dets_t   = (const float*)d_in[0];
  const float* dets_t1  = (const float*)d_in[1];
  const float* W_enc    = (const float*)d_in[2];
  const float* b_enc    = (const float*)d_in[3];
  const float* Wq       = (const float*)d_in[4];
  const float* bq       = (const float*)d_in[5];
  const float* Wk       = (const float*)d_in[6];
  const float* bk       = (const float*)d_in[7];
  const float* Wv       = (const float*)d_in[8];
  const float* bv       = (const float*)d_in[9];
  const float* Wi       = (const float*)d_in[10];
  const float* Wh       = (const float*)d_in[11];
  const float* bi       = (const float*)d_in[12];
  const float* bh       = (const float*)d_in[13];
  const float* W1       = (const float*)d_in[14];
  const float* b1       = (const float*)d_in[15];
  const float* W2       = (const float*)d_in[16];
  const float* b2       = (const float*)d_in[17];
  const float* slots_mu = (const float*)d_in[18];
  const float* init_noise = (const float*)d_in[19];

  char* ws = (char*)d_ws;
  bf16*  x_pre  = (bf16*)(ws + OFF_XPRE);
  bf16*  attn   = (bf16*)(ws + OFF_ATT);
  float* pA     = (float*)(ws + OFF_PA);
  float* p0     = (float*)(ws + OFF_P0);
  float* p1     = (float*)(ws + OFF_P1);
  bf16*  Wenc_t = (bf16*)(ws + OFF_WET);
  bf16*  Wqk_t  = (bf16*)(ws + OFF_WQKT);
  bf16*  W1_t   = (bf16*)(ws + OFF_W1T);
  bf16*  W2_t   = (bf16*)(ws + OFF_W2T);
  bf16*  Wh_b   = (bf16*)(ws + OFF_WHB);
  bf16*  Wvit   = (bf16*)(ws + OFF_WVIT);
  bf16*  Wi_b   = (bf16*)(ws + OFF_WIB);
  bf16*  Wv_bf  = (bf16*)(ws + OFF_WVB);
  bf16*  Wq_bf  = (bf16*)(ws + OFF_WQB);
  bf16*  Wk_bf  = (bf16*)(ws + OFF_WKB);
  bf16*  x      = (bf16*)(ws + OFF_X);
  bf16*  xT     = (bf16*)(ws + OFF_XT);
  float* slots  = (float*)(ws + OFF_SL);
  bf16*  slotspb= (bf16*)(ws + OFF_SLPB);
  bf16*  lnb    = (bf16*)(ws + OFF_LNB);
  bf16*  qkb    = (bf16*)(ws + OFF_QKB);
  bf16*  tb     = (bf16*)(ws + OFF_TB);
  bf16*  hidb   = (bf16*)(ws + OFF_HIDB);
  float* prevs  = (float*)(ws + OFF_PRV);
  float* colsum = (float*)(ws + OFF_CS);
  float* cbuf   = colsum + 64;
  float* bvi    = (float*)(ws + OFF_BVI);
  float* wqbk   = (float*)(ws + OFF_WQBK);
  float* bqk    = (float*)(ws + OFF_BQK);
  float2* stats = (float2*)(ws + OFF_STAT);

  // ---- setup: one mega kernel + folded GEMM pair (2 dispatches) ----
  setup_all<<<14848, 256, 0, stream>>>(W_enc, W1, W2, Wenc_t, W1_t, W2_t,
                                       Wh, Wi, Wv, Wq, Wk, Wh_b, Wi_b, Wv_bf, Wq_bf, Wk_bf,
                                       bv, bk, bq, bi, bvi, wqbk, bqk);
  gemm_setup_pair<<<256, 256, 0, stream>>>(Wi_b, Wv_bf, Wvit, Wk_bf, Wq_bf, Wqk_t);

  auto frame = [&](const float* dets, bool first) {
    gemm_enc<<<1024, 256, 0, stream>>>(dets, Wenc_t, b_enc, x_pre, N_DET, DD, DIN);
    ln_stats<<<4096, 256, 0, stream>>>(x_pre, stats);
    norm_transpose<<<dim3(256, 16), 256, 0, stream>>>(x_pre, stats, x, xT);
    if (first) slots_init_ln<<<64, 256, 0, stream>>>(slots_mu, init_noise, slots, slotspb, lnb, wqbk, cbuf, colsum);
    // frame 2: frame 1's last mlp2_reduce_ln already produced slotspb/lnb/cbuf/colsum (+prevs)
    for (int it = 0; it < 3; ++it) {
      gemm_skinny_e<1><<<dim3(16, 1), 256, 0, stream>>>(lnb, Wqk_t, nullptr, qkb, bqk, DD, DD, DD);
      qk_softmax<<<256, 256, 0, stream>>>(qkb, x, cbuf, attn, colsum);
      gemm_skinny_e<0><<<dim3(16, 16), 256, 0, stream>>>(attn, xT, pA, nullptr, nullptr, DD, N_DET, 1024);
      updates_reduce2<16><<<dim3(4, 64), 256, 0, stream>>>(pA, colsum, tb);
      gemm_skinny_dual<<<dim3(48, 1, 2), 256, 0, stream>>>(tb, slotspb, Wvit, Wh_b, p0, p1, TD, DD, DD);
      gru_reduce_ln<<<64, 256, 0, stream>>>(p0, p1, bvi, bh, slots, lnb);
      gemm_skinny_e<2><<<dim3(32, 1), 256, 0, stream>>>(lnb, W1_t, nullptr, hidb, b1, HH, DD, DD);
      gemm_skinny_e<0><<<dim3(16, 2), 256, 0, stream>>>(hidb, W2_t, pA, nullptr, nullptr, DD, HH, 1024);
      mlp2_reduce_ln<2><<<64, 256, 0, stream>>>(pA, b2, slots, slotspb, lnb, wqbk, cbuf, colsum,
                                                (first && it == 2) ? prevs : nullptr);
    }
  };

  frame(dets_t, true);
  frame(dets_t1, false);

  float* outf = (float*)d_out;
  sim_fused<<<KSLOT, 256, 0, stream>>>(prevs, slots, outf + 64);
  match_kernel<<<1, 64, 0, stream>>>(outf + 64, outf);
}